// Round 3
// baseline (2379.264 us; speedup 1.0000x reference)
//
#include <hip/hip_runtime.h>
#include <math.h>

// 2-layer LSTM (H=512), T=1024 teacher steps + 64 AR steps; only batch row 255
// reaches the output -> single-sequence LSTM. 64 persistent WGs, weights
// register-pinned via opaque asm.
//
// R8 = R7 compute + BARRIERLESS intra-WG sync + pipelined IC poll:
//  * IC poll keeps two samples in flight (issue next pair of loads BEFORE
//    testing the previous) -> detection ~1.0 poll period after visibility
//    instead of ~1.5.
//  * bar1 replaced by 8 per-wave gen-tagged LDS flags: wave rg stages lines
//    [8rg,8rg+8) into hvf then RELEASE-stores flg[g&1][rg]=g (lgkmcnt drain
//    orders all 64 lanes' ds_writes); reader lane sg ACQUIRE-spins
//    flg[g&1][sg>>3] (covers exactly its line sg), then reads its 16 floats.
//  * bar2 replaced by gen-tagged hout pairs: every wave's lanes 0/1 store
//    (g+1|h) into hout64; wave 0's lanes 0..15 spin per-pair and relay each
//    to the comm line as soon as it lands (still one coalesced 128B wave
//    store -- R6 proved scattered publishes are catastrophic).
//  Causality (no fences needed, value-dependency only):
//   - any wave's stage@g+2 <= remote WGs published g+2 <= they saw MY line
//     @g+1 <= my relay@g+1 <= all my waves' hout@g+1 <= every local lane
//     passed waitline@g and its c-reads fed the dots  => LDS parity slots,
//     flags and hout can never be overwritten while a reader needs them.
//   - wave (wg>>3) of each WG polls its OWN line, so stage@g+1 cannot pass
//     until the local relay@g+1 completed all 16 pairs => hout protected.
//
// Comm protocol (R5, proven): pair = (gen<<32 | bitcast(h)) as relaxed
// agent-scope b64 atomics; a WG's line is 16 pairs = 128B published as one
// coalesced wave store. Lane t polls pairs {2j,2j+1} of line t>>3: detection
// and data in ONE IC round trip; 8B atomicity forbids torn reads.

#define G     64      // workgroups
#define NT    512     // threads/wg
#define HD    512     // hidden
#define TT    1024    // teacher steps
#define PRED  64      // prediction length
#define LINEF 64      // floats per comm line slot (256 B); pairs in words 0..31
#define SLOTF (G*LINEF)
#define LSTR  20      // hvf line stride in floats (16 data + 4 pad, 16B-aligned)
#define AS    __HIP_MEMORY_SCOPE_AGENT
#define WS    __HIP_MEMORY_SCOPE_WORKGROUP

typedef unsigned long long u64;

#define LOG2E  1.44269504088896340736f

// opaque register pin: makes the asm the producer of the value so the
// compiler cannot rematerialize the original global load inside the loop
#define KEEP4(v) asm volatile("" : "+v"(v.x), "+v"(v.y), "+v"(v.z), "+v"(v.w))

__device__ __forceinline__ float sigf(float x){
  // 1/(1+exp(-x)) via v_exp_f32 + v_rcp_f32 (err ~1e-6, threshold 3.6e-4)
  return __builtin_amdgcn_rcpf(1.0f + __builtin_amdgcn_exp2f(-LOG2E * x));
}
__device__ __forceinline__ float tanhf_fast(float x){
  float e = __builtin_amdgcn_exp2f(2.0f * LOG2E * x);
  return 1.0f - 2.0f * __builtin_amdgcn_rcpf(e + 1.0f);
}
__device__ __forceinline__ float dot4(float4 a, float4 b){
  return a.x*b.x + a.y*b.y + a.z*b.z + a.w*b.w;
}

__global__ __launch_bounds__(NT, 1) void lstm2_kernel(
    const float* __restrict__ input,
    const float* __restrict__ Wih1, const float* __restrict__ Whh1,
    const float* __restrict__ bih1, const float* __restrict__ bhh1,
    const float* __restrict__ Wih2, const float* __restrict__ Whh2,
    const float* __restrict__ bih2, const float* __restrict__ bhh2,
    const float* __restrict__ Wlin, const float* __restrict__ blin,
    float* __restrict__ out, float* __restrict__ ws)
{
  // hvf[parity][line][0..15]: floats 0-7 = h1 units 8*line..+7,
  //                           floats 8-15 = h2 units 8*line..+7
  __shared__ __align__(16) float hvf[2][G][LSTR];
  __shared__ u64 flg[2][8];     // per-wave stage-complete flags (gen value)
  __shared__ u64 hout64[16];    // gen-tagged gate results: [rg]=h1, [8+rg]=h2
  __shared__ __align__(16) float xrow[TT];

  float* comm = ws;             // [2][G][LINEF]

  const int t  = threadIdx.x;
  const int wg = blockIdx.x;
  const int rg = t >> 6;        // wave id 0..7
  const int sg = t & 63;        // lane
  const int U  = wg*8 + rg;     // hidden unit this wave owns (both layers)

  ((float2*)xrow)[t] = ((const float2*)(input + 255*TT))[t];
  if (t < 16){
    hout64[t] = 0;              // gen 0 (first relay expects gen 1)
    ((u64*)flg)[t] = ~0ull;     // != any real gen
  }

  // ---- weight preload: wave owns the 4 gate rows of unit U of both layers.
  // Row for gate q: R = q*HD + U. Lane sg covers cols [8sg, 8sg+8).
  float4 w1[4][2], w2x[4][2], w2h[4][2];
  #pragma unroll
  for (int q=0;q<4;q++){
    const int R = q*HD + U;
    const float* pa = Whh1 + R*HD + sg*8;
    w1[q][0]  = *(const float4*)(pa);
    w1[q][1]  = *(const float4*)(pa+4);
    const float* pb = Wih2 + R*HD + sg*8;
    w2x[q][0] = *(const float4*)(pb);
    w2x[q][1] = *(const float4*)(pb+4);
    const float* pc = Whh2 + R*HD + sg*8;
    w2h[q][0] = *(const float4*)(pc);
    w2h[q][1] = *(const float4*)(pc+4);
  }
  #pragma unroll
  for (int q=0;q<4;q++){
    KEEP4(w1[q][0]);  KEEP4(w1[q][1]);
    KEEP4(w2x[q][0]); KEEP4(w2x[q][1]);
    KEEP4(w2h[q][0]); KEEP4(w2h[q][1]);
  }

  // lane 0 computes L1 unit U, lane 1 computes L2 unit U
  float bias[4]={0,0,0,0}, wx[4]={0,0,0,0};
  if (sg < 2){
    const float* bi = sg ? bih2 : bih1;
    const float* bh = sg ? bhh2 : bhh1;
    #pragma unroll
    for (int q=0;q<4;q++){
      const int R = q*HD + U;
      bias[q] = bi[R] + bh[R];
      if (sg == 0) wx[q] = Wih1[R];
    }
  }
  float4 wl0 = *(const float4*)(Wlin + sg*8);
  float4 wl1 = *(const float4*)(Wlin + sg*8 + 4);
  const float blin0 = blin[0];

  float cst  = 0.f;     // persistent cell state (lane 0: c1_U, lane 1: c2_U)
  float hcur = 0.f;     // last h this lane produced (re-published every tick)

  // ---- stage tick g: pipelined IC poll of own 2 pairs (line w=t>>3,
  // pairs {2j,2j+1}, j=t&7), write the 2 floats to hvf, release wave flag.
  auto stage = [&](unsigned g){
    const int w = t >> 3, j = t & 7;
    const u64* dq = (const u64*)(comm + (g & 1u)*SLOTF + w*LINEF) + 2*j;
    u64 a0 = __hip_atomic_load(dq,     __ATOMIC_RELAXED, AS);
    u64 a1 = __hip_atomic_load(dq + 1, __ATOMIC_RELAXED, AS);
    for(;;){
      u64 b0 = __hip_atomic_load(dq,     __ATOMIC_RELAXED, AS);  // in flight
      u64 b1 = __hip_atomic_load(dq + 1, __ATOMIC_RELAXED, AS);  // during test
      if (((unsigned)(a0 >> 32) == g) && ((unsigned)(a1 >> 32) == g)) break;
      a0 = b0; a1 = b1;
    }
    float2 fv;
    fv.x = __builtin_bit_cast(float, (unsigned)a0);
    fv.y = __builtin_bit_cast(float, (unsigned)a1);
    *(float2*)&hvf[g & 1u][w][2*j] = fv;
    if (sg == 0)
      __hip_atomic_store(&flg[g & 1u][rg], (u64)g, __ATOMIC_RELEASE, WS);
  };

  // lane sg needs exactly line sg, staged by wave sg>>3
  auto waitline = [&](unsigned g){
    while (__hip_atomic_load(&flg[g & 1u][sg >> 3], __ATOMIC_ACQUIRE, WS)
           != (u64)g) {}
  };

  // ---- one tick: per-wave dots + butterfly + lane-0/1 gate math, gen-tagged
  // hout handoff, wave-0 per-pair spin-relay (coalesced 128B publish).
  auto tick = [&](unsigned g, bool d1, bool d2, float xv){
    const float4 c0 = *(const float4*)&hvf[g & 1u][sg][0];
    const float4 c1 = *(const float4*)&hvf[g & 1u][sg][4];
    const float4 c2 = *(const float4*)&hvf[g & 1u][sg][8];
    const float4 c3 = *(const float4*)&hvf[g & 1u][sg][12];
    float v[8];   // v[0..3]=gates i,f,g,o of L1 unit U; v[4..7]=L2 unit U
    #pragma unroll
    for (int k=0;k<4;k++){
      v[k]   = dot4(w1[k][0],c0) + dot4(w1[k][1],c1);
      v[4+k] = dot4(w2x[k][0],c0) + dot4(w2x[k][1],c1)
             + dot4(w2h[k][0],c2) + dot4(w2h[k][1],c3);
    }
    // butterfly reduce-scatter: afterwards lane(j)=bitrev3(j) holds sum v[j]
    const int b0 = sg & 1, b1 = (sg>>1)&1, b2 = (sg>>2)&1;
    float k4[4];
    #pragma unroll
    for (int k=0;k<4;k++){
      float x = b0 ? v[k] : v[k+4];
      float y = __shfl_xor(x, 1, 64);
      k4[k] = (b0 ? v[k+4] : v[k]) + y;
    }
    float k2[2];
    #pragma unroll
    for (int k=0;k<2;k++){
      float x = b1 ? k4[k] : k4[k+2];
      float y = __shfl_xor(x, 2, 64);
      k2[k] = (b1 ? k4[k+2] : k4[k]) + y;
    }
    float k1;
    {
      float x = b2 ? k2[0] : k2[1];
      float y = __shfl_xor(x, 4, 64);
      k1 = (b2 ? k2[1] : k2[0]) + y;
    }
    k1 += __shfl_xor(k1, 8, 64);
    k1 += __shfl_xor(k1, 16, 64);
    k1 += __shfl_xor(k1, 32, 64);
    // gather gates of unit U for lane p (p=0: L1, p=1: L2).
    // value j lives at lane bitrev3(j): i->lane p, f->4+p, g->2+p, o->6+p.
    const int p = sg & 1;
    float pi = __shfl(k1, p,     64);
    float pf = __shfl(k1, 4 + p, 64);
    float pg = __shfl(k1, 2 + p, 64);
    float po = __shfl(k1, 6 + p, 64);
    const float xb = p ? 0.f : xv;
    pi += xb*wx[0] + bias[0];
    pf += xb*wx[1] + bias[1];
    pg += xb*wx[2] + bias[2];
    po += xb*wx[3] + bias[3];
    const bool act = p ? d2 : d1;       // lanes >=2 compute garbage, never read
    float cn = sigf(pf)*cst + sigf(pi)*tanhf_fast(pg);
    float hn = sigf(po)*tanhf_fast(cn);
    if (act){ cst = cn; hcur = hn; }
    if (sg < 2)
      __hip_atomic_store(&hout64[rg + 8*p],
          ((u64)(g + 1u) << 32) | (u64)__builtin_bit_cast(unsigned, hcur),
          __ATOMIC_RELAXED, WS);
    // wave 0 relays each pair as soon as it lands; lanes 0..15 -> one
    // coalesced 128B line store
    if (rg == 0 && t < 16){
      u64 pr;
      do {
        pr = __hip_atomic_load(&hout64[t], __ATOMIC_RELAXED, WS);
      } while ((unsigned)(pr >> 32) != g + 1u);
      __hip_atomic_store((u64*)(comm + ((g+1u) & 1u)*SLOTF + wg*LINEF) + t,
                         pr, __ATOMIC_RELAXED, AS);
    }
  };

  // o = Wlin . h2 + blin from hvf floats 8..15; per-wave, result in ALL lanes
  auto computeO = [&](unsigned g)->float{
    const float4 c2 = *(const float4*)&hvf[g & 1u][sg][8];
    const float4 c3 = *(const float4*)&hvf[g & 1u][sg][12];
    float s = dot4(wl0, c2) + dot4(wl1, c3);
    #pragma unroll
    for (int m=1;m<64;m<<=1) s += __shfl_xor(s, m, 64);
    return s + blin0;
  };

  __syncthreads();   // xrow + LDS init visible (only barrier in the kernel)

  unsigned g = 0;

  // ---- teacher: tick g computes L1 step g || L2 step g-1 ----
  for (int tk=0; tk<TT; ++tk, ++g){
    stage(g); waitline(g);               // hvf = [h1_{g-1} | h2_{g-2}]
    tick(g, true, tk >= 1, xrow[tk]);    // publish [h1_g | h2_{g-1}] pairs
  }

  // ---- drain: L2 step 1023 ----
  stage(g); waitline(g);                 // [h1_1023 | h2_1022]
  tick(g, false, true, 0.f);             // publish [h1_1023 | h2_1023]
  ++g;

  // ---- AR: steps s = 1024..1086, 2 ticks each ----
  for (int s=TT; s<TT+PRED-1; ++s){
    stage(g); waitline(g);               // [h1_{s-1} | h2_{s-1}]
    float xv = computeO(g);              // o_{s-1}, all waves redundantly
    if (wg == 0 && t == 0) out[s - TT] = xv;
    tick(g, true, false, xv);            // publish [h1_s | h2_{s-1}]
    ++g;

    stage(g); waitline(g);               // [h1_s | h2_{s-1}]
    tick(g, false, true, 0.f);           // publish [h1_s | h2_s]
    ++g;
  }

  // ---- final output o_1086 ----
  stage(g); waitline(g);                 // [h1_1086 | h2_1086]
  float xv = computeO(g);
  if (wg == 0 && t == 0) out[PRED - 1] = xv;
}

extern "C" void kernel_launch(void* const* d_in, const int* in_sizes, int n_in,
                              void* d_out, int out_size, void* d_ws, size_t ws_size,
                              hipStream_t stream) {
  const float* input = (const float*)d_in[0];
  // d_in[1] = pred_len (fixed 64, baked in)
  const float* Wih1 = (const float*)d_in[2];
  const float* Whh1 = (const float*)d_in[3];
  const float* bih1 = (const float*)d_in[4];
  const float* bhh1 = (const float*)d_in[5];
  const float* Wih2 = (const float*)d_in[6];
  const float* Whh2 = (const float*)d_in[7];
  const float* bih2 = (const float*)d_in[8];
  const float* bhh2 = (const float*)d_in[9];
  const float* Wlin = (const float*)d_in[10];
  const float* blin = (const float*)d_in[11];

  // zero comm: u64 zero pairs == (gen 0, h=0.0f) -> valid initial state
  hipMemsetAsync(d_ws, 0, 2 * SLOTF * sizeof(float), stream);

  lstm2_kernel<<<dim3(G), dim3(NT), 0, stream>>>(
      input, Wih1, Whh1, bih1, bhh1, Wih2, Whh2, bih2, bhh2, Wlin, blin,
      (float*)d_out, (float*)d_ws);
}

// Round 6
// 2207.635 us; speedup vs baseline: 1.0777x; 1.0777x over previous
//
#include <hip/hip_runtime.h>
#include <math.h>

// 2-layer LSTM (H=512), T=1024 teacher steps + 64 AR steps; only batch row 255
// reaches the output -> single-sequence LSTM. 64 persistent WGs, weights
// register-pinned via opaque asm (VGPR_Count=88 proved re-load otherwise).
//
// R11 = R7 (proven: 2029us, passed) + PIPELINED b64-atomic poll (from R8,
// which passed correctness; its regression was the LDS flag/spin layout,
// not the poll). Two samples in flight: test the older sample while the
// newer is still flying -> detection ~1.0 poll period after visibility
// instead of ~1.5, and per-WG detection jitter tightens (less max-over-64
// straggle per tick).
//
// R9/R10 lesson (paid twice): a plain global_load_dwordx4 over two 8B pairs
// is NOT per-8B single-copy atomic vs concurrent 8B stores -- it can return
// h-old/gen-new within one pair (deterministic absmax 1e-2). Pair integrity
// requires real atomic instructions: poll stays __hip_atomic_load on u64.
// R8 lesson: LDS flag/hout spin sync costs +290us (bank conflicts + 120cy
// LDS spin granularity on the critical path). HW barriers are cheap; keep.
// R6 lesson: publish must stay ONE coalesced 128B wave store (scattered
// per-wave 8B publishes: 4x WRITE_SIZE, 2x dur, livelock outlier).
//
// Comm protocol (R5, proven): pair = (gen<<32 | bitcast(h)); a WG's line is
// 16 pairs = 128B published as one coalesced wave store (16 lanes x 8B agent
// atomics). Lane t polls pairs {2j,2j+1} of line t>>3: detection and data in
// ONE IC round trip; 8B atomicity forbids torn reads; slot-reuse safe by
// value-dependency causality.
// Per-wave gate math (wave rg owns unit U=wg*8+rg of both layers) computed
// BEFORE the handoff barrier; wave 0's post-barrier path is only LDS read ->
// pack -> 128B store.
// hvec chunk stride padded 256->264 words (4-way staging conflicts otherwise).

#define G     64      // workgroups
#define NT    512     // threads/wg
#define HD    512     // hidden
#define TT    1024    // teacher steps
#define PRED  64      // prediction length
#define LINEF 64      // floats per comm line slot (256 B); pairs in words 0..31
#define SLOTF (G*LINEF)
#define STR   264     // hvec chunk stride in words (256 data + 8 pad banks)
#define AS    __HIP_MEMORY_SCOPE_AGENT

typedef unsigned long long u64;

#define LOG2E  1.44269504088896340736f

// opaque register pin: makes the asm the producer of the value so the
// compiler cannot rematerialize the original global load inside the loop
#define KEEP4(v) asm volatile("" : "+v"(v.x), "+v"(v.y), "+v"(v.z), "+v"(v.w))

__device__ __forceinline__ float sigf(float x){
  // 1/(1+exp(-x)) via v_exp_f32 + v_rcp_f32 (err ~1e-6, threshold 3.6e-4)
  return __builtin_amdgcn_rcpf(1.0f + __builtin_amdgcn_exp2f(-LOG2E * x));
}
__device__ __forceinline__ float tanhf_fast(float x){
  float e = __builtin_amdgcn_exp2f(2.0f * LOG2E * x);
  return 1.0f - 2.0f * __builtin_amdgcn_rcpf(e + 1.0f);
}
__device__ __forceinline__ float dot4(float4 a, float4 b){
  return a.x*b.x + a.y*b.y + a.z*b.z + a.w*b.w;
}

__global__ __launch_bounds__(NT, 1) void lstm2_kernel(
    const float* __restrict__ input,
    const float* __restrict__ Wih1, const float* __restrict__ Whh1,
    const float* __restrict__ bih1, const float* __restrict__ bhh1,
    const float* __restrict__ Wih2, const float* __restrict__ Whh2,
    const float* __restrict__ bih2, const float* __restrict__ bhh2,
    const float* __restrict__ Wlin, const float* __restrict__ blin,
    float* __restrict__ out, float* __restrict__ ws)
{
  // hvec chunk c (c=0..3) = words [c*STR, c*STR+256):
  //   c0: h1 units {8w..8w+3} of line w at word 4w   c1: h1 units {8w+4..8w+7}
  //   c2: h2 units {8w..8w+3}                        c3: h2 units {8w+4..8w+7}
  __shared__ __align__(16) float hvec[4*STR];
  __shared__ __align__(16) float xrow[TT];
  __shared__ float hout[16];    // per-wave gate results: [rg]=h1_U, [8+rg]=h2_U

  float* comm = ws;             // [2][G][LINEF]

  const int t  = threadIdx.x;
  const int wg = blockIdx.x;
  const int rg = t >> 6;        // wave id 0..7
  const int sg = t & 63;        // lane
  const int U  = wg*8 + rg;     // hidden unit this wave owns (both layers)

  ((float2*)xrow)[t] = ((const float2*)(input + 255*TT))[t];

  // ---- weight preload: wave owns the 4 gate rows of unit U of both layers.
  // Row for gate q: R = q*HD + U. Lane sg covers cols [8sg, 8sg+8).
  float4 w1[4][2], w2x[4][2], w2h[4][2];
  #pragma unroll
  for (int q=0;q<4;q++){
    const int R = q*HD + U;
    const float* pa = Whh1 + R*HD + sg*8;
    w1[q][0]  = *(const float4*)(pa);
    w1[q][1]  = *(const float4*)(pa+4);
    const float* pb = Wih2 + R*HD + sg*8;
    w2x[q][0] = *(const float4*)(pb);
    w2x[q][1] = *(const float4*)(pb+4);
    const float* pc = Whh2 + R*HD + sg*8;
    w2h[q][0] = *(const float4*)(pc);
    w2h[q][1] = *(const float4*)(pc+4);
  }
  #pragma unroll
  for (int q=0;q<4;q++){
    KEEP4(w1[q][0]);  KEEP4(w1[q][1]);
    KEEP4(w2x[q][0]); KEEP4(w2x[q][1]);
    KEEP4(w2h[q][0]); KEEP4(w2h[q][1]);
  }

  // lane 0 computes L1 unit U, lane 1 computes L2 unit U
  float bias[4]={0,0,0,0}, wx[4]={0,0,0,0};
  if (sg < 2){
    const float* bi = sg ? bih2 : bih1;
    const float* bh = sg ? bhh2 : bhh1;
    #pragma unroll
    for (int q=0;q<4;q++){
      const int R = q*HD + U;
      bias[q] = bi[R] + bh[R];
      if (sg == 0) wx[q] = Wih1[R];
    }
  }
  float4 wl0 = *(const float4*)(Wlin + sg*8);
  float4 wl1 = *(const float4*)(Wlin + sg*8 + 4);
  const float blin0 = blin[0];

  float cst  = 0.f;     // persistent cell state (lane 0: c1_U, lane 1: c2_U)
  float hcur = 0.f;     // last h this lane produced (re-published every tick)

  // ---- consume tick g: all 512 threads. Lane t owns pairs {2j,2j+1} of line
  // w (w=t>>3, j=t&7). PIPELINED spin: keep the next sample in flight while
  // testing the previous -> detection ~1 poll period after visibility.
  // Value rides with its gen in one 8B atom -> no torn pairs, no fence.
  auto poll_stage = [&](unsigned g){
    const int w = t >> 3, j = t & 7;
    const u64* dq = (const u64*)(comm + (g & 1u)*SLOTF + w*LINEF) + 2*j;
    u64 a0 = __hip_atomic_load(dq,     __ATOMIC_RELAXED, AS);
    u64 a1 = __hip_atomic_load(dq + 1, __ATOMIC_RELAXED, AS);
    for(;;){
      u64 b0 = __hip_atomic_load(dq,     __ATOMIC_RELAXED, AS);  // in flight
      u64 b1 = __hip_atomic_load(dq + 1, __ATOMIC_RELAXED, AS);  // during test
      if (((unsigned)(a0 >> 32) == g) && ((unsigned)(a1 >> 32) == g)) break;
      a0 = b0; a1 = b1;
    }
    const int c  = j >> 1;
    const int wd = c*STR + 4*w + 2*(j & 1);
    float2 fv;
    fv.x = __builtin_bit_cast(float, (unsigned)a0);
    fv.y = __builtin_bit_cast(float, (unsigned)a1);
    *(float2*)(hvec + wd) = fv;
    __syncthreads();
  };

  // ---- one tick: per-wave dots + butterfly + lane-0/1 gate math (parallel
  // across waves, BEFORE the barrier) -> LDS handoff -> wave 0 publishes the
  // whole line as one coalesced 128B store (minimal post-barrier path).
  auto tick = [&](unsigned g, bool d1, bool d2, float xv){
    const float4 c0 = ((const float4*)(hvec + 0*STR))[sg];
    const float4 c1 = ((const float4*)(hvec + 1*STR))[sg];
    const float4 c2 = ((const float4*)(hvec + 2*STR))[sg];
    const float4 c3 = ((const float4*)(hvec + 3*STR))[sg];
    float v[8];   // v[0..3]=gates i,f,g,o of L1 unit U; v[4..7]=L2 unit U
    #pragma unroll
    for (int k=0;k<4;k++){
      v[k]   = dot4(w1[k][0],c0) + dot4(w1[k][1],c1);
      v[4+k] = dot4(w2x[k][0],c0) + dot4(w2x[k][1],c1)
             + dot4(w2h[k][0],c2) + dot4(w2h[k][1],c3);
    }
    // butterfly reduce-scatter: afterwards lane(j)=bitrev3(j) holds sum v[j]
    const int b0 = sg & 1, b1 = (sg>>1)&1, b2 = (sg>>2)&1;
    float k4[4];
    #pragma unroll
    for (int k=0;k<4;k++){
      float x = b0 ? v[k] : v[k+4];
      float y = __shfl_xor(x, 1, 64);
      k4[k] = (b0 ? v[k+4] : v[k]) + y;
    }
    float k2[2];
    #pragma unroll
    for (int k=0;k<2;k++){
      float x = b1 ? k4[k] : k4[k+2];
      float y = __shfl_xor(x, 2, 64);
      k2[k] = (b1 ? k4[k+2] : k4[k]) + y;
    }
    float k1;
    {
      float x = b2 ? k2[0] : k2[1];
      float y = __shfl_xor(x, 4, 64);
      k1 = (b2 ? k2[1] : k2[0]) + y;
    }
    k1 += __shfl_xor(k1, 8, 64);
    k1 += __shfl_xor(k1, 16, 64);
    k1 += __shfl_xor(k1, 32, 64);
    // gather gates of unit U for lane p (p=0: L1, p=1: L2).
    // value j lives at lane bitrev3(j): i->lane p, f->4+p, g->2+p, o->6+p.
    const int p = sg & 1;
    float pi = __shfl(k1, p,     64);
    float pf = __shfl(k1, 4 + p, 64);
    float pg = __shfl(k1, 2 + p, 64);
    float po = __shfl(k1, 6 + p, 64);
    const float xb = p ? 0.f : xv;
    pi += xb*wx[0] + bias[0];
    pf += xb*wx[1] + bias[1];
    pg += xb*wx[2] + bias[2];
    po += xb*wx[3] + bias[3];
    const bool act = p ? d2 : d1;       // lanes >=2 compute garbage, never read
    float cn = sigf(pf)*cst + sigf(pi)*tanhf_fast(pg);
    float hn = sigf(po)*tanhf_fast(cn);
    if (act){ cst = cn; hcur = hn; }
    if (sg < 2) hout[rg + 8*p] = hcur;    // [rg]=h1_U, [8+rg]=h2_U
    __syncthreads();                      // barrier 2: handoff + hvec-reuse
    if (t < 16){
      u64 pr = ((u64)(g + 1u) << 32)
             | (u64)__builtin_bit_cast(unsigned, hout[t]);
      u64* nb = (u64*)(comm + ((g+1u) & 1u)*SLOTF + wg*LINEF);
      __hip_atomic_store(nb + t, pr, __ATOMIC_RELAXED, AS);
    }
  };

  // o = Wlin . h2 + blin from hvec chunks 2/3; per-wave, result in ALL lanes
  auto computeO = [&](){
    float s = dot4(wl0, ((const float4*)(hvec + 2*STR))[sg])
            + dot4(wl1, ((const float4*)(hvec + 3*STR))[sg]);
    #pragma unroll
    for (int m=1;m<64;m<<=1) s += __shfl_xor(s, m, 64);
    return s + blin0;
  };

  __syncthreads();   // xrow staged

  unsigned g = 0;

  // ---- teacher: tick g computes L1 step g || L2 step g-1 ----
  for (int tk=0; tk<TT; ++tk, ++g){
    poll_stage(g);                       // hvec = [h1_{g-1} | h2_{g-2}]
    tick(g, true, tk >= 1, xrow[tk]);    // publish [h1_g | h2_{g-1}] pairs
  }

  // ---- drain: L2 step 1023 ----
  poll_stage(g);                         // [h1_1023 | h2_1022]
  tick(g, false, true, 0.f);             // publish [h1_1023 | h2_1023]
  ++g;

  // ---- AR: steps s = 1024..1086, 2 ticks each ----
  for (int s=TT; s<TT+PRED-1; ++s){
    poll_stage(g);                       // [h1_{s-1} | h2_{s-1}]
    float xv = computeO();               // o_{s-1}, all waves redundantly
    if (wg == 0 && t == 0) out[s - TT] = xv;
    tick(g, true, false, xv);            // publish [h1_s | h2_{s-1}]
    ++g;

    poll_stage(g);                       // [h1_s | h2_{s-1}]
    tick(g, false, true, 0.f);           // publish [h1_s | h2_s]
    ++g;
  }

  // ---- final output o_1086 ----
  poll_stage(g);                         // [h1_1086 | h2_1086]
  float xv = computeO();
  if (wg == 0 && t == 0) out[PRED - 1] = xv;
}

extern "C" void kernel_launch(void* const* d_in, const int* in_sizes, int n_in,
                              void* d_out, int out_size, void* d_ws, size_t ws_size,
                              hipStream_t stream) {
  const float* input = (const float*)d_in[0];
  // d_in[1] = pred_len (fixed 64, baked in)
  const float* Wih1 = (const float*)d_in[2];
  const float* Whh1 = (const float*)d_in[3];
  const float* bih1 = (const float*)d_in[4];
  const float* bhh1 = (const float*)d_in[5];
  const float* Wih2 = (const float*)d_in[6];
  const float* Whh2 = (const float*)d_in[7];
  const float* bih2 = (const float*)d_in[8];
  const float* bhh2 = (const float*)d_in[9];
  const float* Wlin = (const float*)d_in[10];
  const float* blin = (const float*)d_in[11];

  // zero comm: u64 zero pairs == (gen 0, h=0.0f) -> valid initial state
  hipMemsetAsync(d_ws, 0, 2 * SLOTF * sizeof(float), stream);

  lstm2_kernel<<<dim3(G), dim3(NT), 0, stream>>>(
      input, Wih1, Whh1, bih1, bhh1, Wih2, Whh2, bih2, bhh2, Wlin, blin,
      (float*)d_out, (float*)d_ws);
}